// Round 7
// baseline (277.420 us; speedup 1.0000x reference)
//
#include <hip/hip_runtime.h>
#include <hip/hip_bf16.h>

typedef unsigned int u32;
typedef unsigned short u16;
typedef __attribute__((ext_vector_type(8))) __bf16 bf16x8;
typedef __attribute__((ext_vector_type(4))) float f32x4;

#define N_CAP 10
#define D_CAP 16
#define NN 160
#define KK 2048

__device__ __forceinline__ u32 pack_hi(float f0, float f1) {
  u32 u0 = __builtin_bit_cast(u32, f0), u1 = __builtin_bit_cast(u32, f1);
  return (u0 >> 16) | (u1 & 0xFFFF0000u);
}
__device__ __forceinline__ float hi_part(float f) {
  u32 u = __builtin_bit_cast(u32, f) & 0xFFFF0000u;
  return __builtin_bit_cast(float, u);
}

__device__ __forceinline__ void gl_lds16(const void* g, void* l) {
  __builtin_amdgcn_global_load_lds((const __attribute__((address_space(1))) void*)g,
                                   (__attribute__((address_space(3))) void*)l, 16, 0, 0);
}

__device__ __forceinline__ void split8(const float4& A, const float4& B,
                                       bf16x8& h, bf16x8& l) {
  union { u32 u[4]; bf16x8 b; } H, L;
  H.u[0] = pack_hi(A.x, A.y); H.u[1] = pack_hi(A.z, A.w);
  H.u[2] = pack_hi(B.x, B.y); H.u[3] = pack_hi(B.z, B.w);
  L.u[0] = pack_hi(A.x - hi_part(A.x), A.y - hi_part(A.y));
  L.u[1] = pack_hi(A.z - hi_part(A.z), A.w - hi_part(A.w));
  L.u[2] = pack_hi(B.x - hi_part(B.x), B.y - hi_part(B.y));
  L.u[3] = pack_hi(B.z - hi_part(B.z), B.w - hi_part(B.w));
  h = H.b; l = L.b;
}

// W[k][n] f32 -> Whi/Wlo bf16 in MFMA-B-fragment order: [(k>>3)][n][k&7]
__global__ void split_w(const float* __restrict__ W, u16* __restrict__ Whi,
                        u16* __restrict__ Wlo) {
  const int tid = blockIdx.x * 256 + threadIdx.x;   // 327680 exact
  const int k = tid / NN, n = tid - k * NN;
  const float f = W[tid];
  const u32 u = __builtin_bit_cast(u32, f);
  const float lo = f - hi_part(f);
  const int dst = ((k >> 3) * NN + n) * 8 + (k & 7);
  Whi[dst] = (u16)(u >> 16);
  Wlo[dst] = (u16)(__builtin_bit_cast(u32, lo) >> 16);
}

// ===================== split-K GEMM: 256 blocks = 128 row-tiles x 2 k-halves ===
#define BMm 128
#define KH 1024
#define BKm 32
#define NSTm (KH / BKm)       // 32
#define THRm 640              // 10 waves
#define PSTRIDE (BMm * NN)    // 20480 f32 per block-entry
#define P_OFF_BYTES (2 * KK * NN * 2)  // after Whi+Wlo = 1310720
#define WS_NEED ((size_t)P_OFF_BYTES + (size_t)256 * PSTRIDE * 4)

__global__ __launch_bounds__(THRm) void gemm_splitk(
    const float* __restrict__ X, const u16* __restrict__ Whi,
    const u16* __restrict__ Wlo, float* __restrict__ P) {
  __shared__ __align__(16) char smem[40960];   // 2 buffers x (Bhi 10240 + Blo 10240)
  const int t = threadIdx.x;
  const int b = blockIdx.x;
  const int rt = b & 127, kh = b >> 7;
  const int rbase = rt * BMm;
  const int lane = t & 63;
  const int w = t >> 6;
  const int wg = (w >= 5) ? 1 : 0;     // row half: rows 64*wg..+64
  const int wc = w - 5 * wg;           // col group: cols 32*wc..+32
  const int l15 = lane & 15, q = lane >> 4;

  // B DMA: per step, hi tile = 4 kc x 160 n x 8 u16 = 10240 B = 640 chunks; 1/thread
  const u16* WhiK = Whi + (size_t)(kh * 128) * 1280 + t * 8;
  const u16* WloK = Wlo + (size_t)(kh * 128) * 1280 + t * 8;
  // per step s: src += s*5120 u16; dst = smem + buf*20480 + (t*16) [+10240 for lo]

  // A fragment sources (direct global, per-lane row)
  const float* gA[4];
#pragma unroll
  for (int m = 0; m < 4; ++m)
    gA[m] = X + (size_t)(rbase + 64 * wg + 16 * m + l15) * KK + kh * KH + q * 8;

  // B fragment LDS offsets (bytes within a buffer)
  const int bofs0 = (q * 160 + 32 * wc + l15) * 16;        // i=0
  const int bofs1 = (q * 160 + 32 * wc + 16 + l15) * 16;   // i=1

  f32x4 acc[4][2];
#pragma unroll
  for (int m = 0; m < 4; ++m)
#pragma unroll
    for (int i = 0; i < 2; ++i) acc[m][i] = (f32x4){0.f, 0.f, 0.f, 0.f};

  float4 aA[4][2], aB[4][2];   // A prefetch regs: steps s (even) / s+1 (odd)

  // ---- prologue ----
  gl_lds16(WhiK, smem + t * 16);
  gl_lds16(WloK, smem + 10240 + t * 16);
#pragma unroll
  for (int m = 0; m < 4; ++m) {
    aA[m][0] = *(const float4*)(gA[m]);
    aA[m][1] = *(const float4*)(gA[m] + 4);
    aB[m][0] = *(const float4*)(gA[m] + BKm);
    aB[m][1] = *(const float4*)(gA[m] + BKm + 4);
  }
  __syncthreads();   // drains B DMA(0)

#define HALFSTEP(S, AREG)                                                        \
  {                                                                              \
    if ((S) + 1 < NSTm) {  /* DMA next B tile into other buffer */               \
      const u16* sh = WhiK + ((S) + 1) * 5120;                                   \
      const u16* sl = WloK + ((S) + 1) * 5120;                                   \
      char* dst = smem + (((S) + 1) & 1) * 20480;                                \
      gl_lds16(sh, dst + t * 16);                                                \
      gl_lds16(sl, dst + 10240 + t * 16);                                        \
    }                                                                            \
    bf16x8 ah[4], al[4];                                                         \
    _Pragma("unroll") for (int m = 0; m < 4; ++m)                                \
      split8(AREG[m][0], AREG[m][1], ah[m], al[m]);                              \
    if ((S) + 2 < NSTm) {  /* reload this reg set for step S+2 */                \
      _Pragma("unroll") for (int m = 0; m < 4; ++m) {                            \
        AREG[m][0] = *(const float4*)(gA[m] + ((S) + 2) * BKm);                  \
        AREG[m][1] = *(const float4*)(gA[m] + ((S) + 2) * BKm + 4);              \
      }                                                                          \
    }                                                                            \
    const char* bb = smem + ((S) & 1) * 20480;                                   \
    bf16x8 bh0 = *(const bf16x8*)(bb + bofs0);                                   \
    bf16x8 bh1 = *(const bf16x8*)(bb + bofs1);                                   \
    bf16x8 bl0 = *(const bf16x8*)(bb + 10240 + bofs0);                           \
    bf16x8 bl1 = *(const bf16x8*)(bb + 10240 + bofs1);                           \
    _Pragma("unroll") for (int m = 0; m < 4; ++m) {                              \
      acc[m][0] = __builtin_amdgcn_mfma_f32_16x16x32_bf16(ah[m], bh0, acc[m][0], 0, 0, 0); \
      acc[m][0] = __builtin_amdgcn_mfma_f32_16x16x32_bf16(ah[m], bl0, acc[m][0], 0, 0, 0); \
      acc[m][0] = __builtin_amdgcn_mfma_f32_16x16x32_bf16(al[m], bh0, acc[m][0], 0, 0, 0); \
      acc[m][1] = __builtin_amdgcn_mfma_f32_16x16x32_bf16(ah[m], bh1, acc[m][1], 0, 0, 0); \
      acc[m][1] = __builtin_amdgcn_mfma_f32_16x16x32_bf16(ah[m], bl1, acc[m][1], 0, 0, 0); \
      acc[m][1] = __builtin_amdgcn_mfma_f32_16x16x32_bf16(al[m], bh1, acc[m][1], 0, 0, 0); \
    }                                                                            \
    __syncthreads();  /* drains DMA(S+1) + A loads; seals buf reads */           \
  }

#pragma unroll 1
  for (int s = 0; s < NSTm; s += 2) {
    HALFSTEP(s, aA)
    HALFSTEP(s + 1, aB)
  }
#undef HALFSTEP

  // ---- store partials: P[b][rr][n], C/D layout col=l15, row=q*4+reg ----
  float* Pb = P + (size_t)b * PSTRIDE;
#pragma unroll
  for (int m = 0; m < 4; ++m)
#pragma unroll
    for (int i = 0; i < 2; ++i)
#pragma unroll
      for (int r = 0; r < 4; ++r) {
        const int rr = 64 * wg + 16 * m + q * 4 + r;
        const int n = 32 * wc + 16 * i + l15;
        Pb[rr * NN + n] = acc[m][i][r];
      }
}

// ===================== reduce partials + routing (proven code) ================
__global__ __launch_bounds__(64) void reduce_route(
    const float* __restrict__ P, float* __restrict__ out) {
  __shared__ float hat[64 * 164];
  const int blk = blockIdx.x;          // 256 blocks, rows blk*64..+64
  const int t = threadIdx.x;
  const int r0 = blk * 64;
  const int rt = r0 >> 7;              // 128-row tile index (uniform in block)
  for (int i = t; i < 64 * NN; i += 64) {
    const int r = i / NN, n = i - r * NN;
    const int rr = (r0 + r) & 127;
    hat[r * 164 + n] = P[(size_t)rt * PSTRIDE + rr * NN + n] +
                       P[(size_t)(128 + rt) * PSTRIDE + rr * NN + n];
  }
  __syncthreads();
  const int r = t;
  float bb[N_CAP];
#pragma unroll
  for (int n = 0; n < N_CAP; ++n) bb[n] = 0.f;
  float v[D_CAP];
#pragma unroll
  for (int it = 0; it < 3; ++it) {
    float mx = bb[0];
#pragma unroll
    for (int n = 1; n < N_CAP; ++n) mx = fmaxf(mx, bb[n]);
    float c[N_CAP], se = 0.f;
#pragma unroll
    for (int n = 0; n < N_CAP; ++n) { c[n] = __expf(bb[n] - mx); se += c[n]; }
    const float inv = 1.f / se;
    float sd[D_CAP], s2 = 0.f;
#pragma unroll
    for (int d = 0; d < D_CAP; ++d) {
      float x = 0.f;
#pragma unroll
      for (int n = 0; n < N_CAP; ++n) x += c[n] * hat[r * 164 + n * D_CAP + d];
      x *= inv;
      sd[d] = x;
      s2 += x * x;
    }
    const float scale = s2 / ((1.f + s2) * sqrtf(s2 + 1e-7f));
#pragma unroll
    for (int d = 0; d < D_CAP; ++d) v[d] = scale * sd[d];
    if (it < 2) {
#pragma unroll
      for (int n = 0; n < N_CAP; ++n) {
        float dd = 0.f;
#pragma unroll
        for (int d = 0; d < D_CAP; ++d) dd += hat[r * 164 + n * D_CAP + d] * v[d];
        bb[n] += dd;
      }
    }
  }
#pragma unroll
  for (int d = 0; d < D_CAP; ++d)
    out[(size_t)(r0 + r) * D_CAP + d] = v[d];
}

// ==================== R5 fallback (proven) if ws too small =================
#define BM 64
#define BK 32
#define NSTEPS (KK / BK)
#define THREADS 640
#define LDST 40
#define AS_TILE (BM * LDST)
#define HAT_STRIDE 164
#define SMEM_BYTES (BM * HAT_STRIDE * 4)
union U4B8 { uint4 u; bf16x8 b; };

__global__ __launch_bounds__(THREADS, 3) void capsule_fb(
    const float* __restrict__ X, const float* __restrict__ W, float* __restrict__ out) {
  __shared__ __align__(16) char smem[SMEM_BYTES];
  u16* As_hi = (u16*)smem;
  u16* As_lo = As_hi + AS_TILE;
  float* hat = (float*)smem;
  const int t = threadIdx.x;
  const int rbase = blockIdx.x * BM;
  const int lane = t & 63;
  const int w = t >> 6;
  const int wip = (w >= 5) ? 1 : 0;
  const int wjp = w - 5 * wip;
  const int l15 = lane & 15;
  const int q = lane >> 4;
  const int ar = t >> 2;
  const int ak = (t & 3) * 8;
  const float* gA = X + (size_t)(rbase + ar) * KK + ak;
  const float* gB = W + (q * 8) * NN + 32 * wjp + l15;
  f32x4 acc00 = {0,0,0,0}, acc01 = {0,0,0,0}, acc10 = {0,0,0,0}, acc11 = {0,0,0,0};
  float4 pa0A, pa1A, pa0B, pa1B;
  if (t < 256) {
    pa0A = *(const float4*)(gA);        pa1A = *(const float4*)(gA + 4);
    pa0B = *(const float4*)(gA + BK);   pa1B = *(const float4*)(gA + BK + 4);
  }
  float buA[16], buB[16];
#pragma unroll
  for (int j = 0; j < 8; ++j) { buA[j] = gB[j * NN]; buA[8 + j] = gB[16 + j * NN]; }
#define STEP(S, PA0, PA1, BU, BNXT)                                              \
  {                                                                              \
    __syncthreads();                                                             \
    if (t < 256) {                                                               \
      uint4 hi, lo;                                                              \
      hi.x = pack_hi(PA0.x, PA0.y); hi.y = pack_hi(PA0.z, PA0.w);                \
      hi.z = pack_hi(PA1.x, PA1.y); hi.w = pack_hi(PA1.z, PA1.w);                \
      lo.x = pack_hi(PA0.x - hi_part(PA0.x), PA0.y - hi_part(PA0.y));            \
      lo.y = pack_hi(PA0.z - hi_part(PA0.z), PA0.w - hi_part(PA0.w));            \
      lo.z = pack_hi(PA1.x - hi_part(PA1.x), PA1.y - hi_part(PA1.y));            \
      lo.w = pack_hi(PA1.z - hi_part(PA1.z), PA1.w - hi_part(PA1.w));            \
      *(uint4*)(As_hi + ar * LDST + ak) = hi;                                    \
      *(uint4*)(As_lo + ar * LDST + ak) = lo;                                    \
    }                                                                            \
    __syncthreads();                                                             \
    if (t < 256 && (S) + 2 < NSTEPS) {                                           \
      PA0 = *(const float4*)(gA + ((S) + 2) * BK);                               \
      PA1 = *(const float4*)(gA + ((S) + 2) * BK + 4);                           \
    }                                                                            \
    if ((S) + 1 < NSTEPS) {                                                      \
      const float* bsrc = gB + ((S) + 1) * (BK * NN);                            \
      _Pragma("unroll")                                                          \
      for (int j = 0; j < 8; ++j) { BNXT[j] = bsrc[j * NN]; BNXT[8 + j] = bsrc[16 + j * NN]; } \
    }                                                                            \
    U4B8 bh0, bl0, bh1, bl1;                                                     \
    bh0.u.x = pack_hi(BU[0], BU[1]);  bh0.u.y = pack_hi(BU[2], BU[3]);           \
    bh0.u.z = pack_hi(BU[4], BU[5]);  bh0.u.w = pack_hi(BU[6], BU[7]);           \
    bh1.u.x = pack_hi(BU[8], BU[9]);  bh1.u.y = pack_hi(BU[10], BU[11]);         \
    bh1.u.z = pack_hi(BU[12], BU[13]); bh1.u.w = pack_hi(BU[14], BU[15]);        \
    float lb[16];                                                                \
    _Pragma("unroll")                                                            \
    for (int j = 0; j < 16; ++j) lb[j] = BU[j] - hi_part(BU[j]);                 \
    bl0.u.x = pack_hi(lb[0], lb[1]);  bl0.u.y = pack_hi(lb[2], lb[3]);           \
    bl0.u.z = pack_hi(lb[4], lb[5]);  bl0.u.w = pack_hi(lb[6], lb[7]);           \
    bl1.u.x = pack_hi(lb[8], lb[9]);  bl1.u.y = pack_hi(lb[10], lb[11]);         \
    bl1.u.z = pack_hi(lb[12], lb[13]); bl1.u.w = pack_hi(lb[14], lb[15]);        \
    bf16x8 ah0 = *(const bf16x8*)(As_hi + (32 * wip + l15) * LDST + q * 8);      \
    bf16x8 ah1 = *(const bf16x8*)(As_hi + (32 * wip + 16 + l15) * LDST + q * 8); \
    bf16x8 al0 = *(const bf16x8*)(As_lo + (32 * wip + l15) * LDST + q * 8);      \
    bf16x8 al1 = *(const bf16x8*)(As_lo + (32 * wip + 16 + l15) * LDST + q * 8); \
    acc00 = __builtin_amdgcn_mfma_f32_16x16x32_bf16(ah0, bh0.b, acc00, 0, 0, 0); \
    acc00 = __builtin_amdgcn_mfma_f32_16x16x32_bf16(ah0, bl0.b, acc00, 0, 0, 0); \
    acc00 = __builtin_amdgcn_mfma_f32_16x16x32_bf16(al0, bh0.b, acc00, 0, 0, 0); \
    acc01 = __builtin_amdgcn_mfma_f32_16x16x32_bf16(ah0, bh1.b, acc01, 0, 0, 0); \
    acc01 = __builtin_amdgcn_mfma_f32_16x16x32_bf16(ah0, bl1.b, acc01, 0, 0, 0); \
    acc01 = __builtin_amdgcn_mfma_f32_16x16x32_bf16(al0, bh1.b, acc01, 0, 0, 0); \
    acc10 = __builtin_amdgcn_mfma_f32_16x16x32_bf16(ah1, bh0.b, acc10, 0, 0, 0); \
    acc10 = __builtin_amdgcn_mfma_f32_16x16x32_bf16(ah1, bl0.b, acc10, 0, 0, 0); \
    acc10 = __builtin_amdgcn_mfma_f32_16x16x32_bf16(al1, bh0.b, acc10, 0, 0, 0); \
    acc11 = __builtin_amdgcn_mfma_f32_16x16x32_bf16(ah1, bh1.b, acc11, 0, 0, 0); \
    acc11 = __builtin_amdgcn_mfma_f32_16x16x32_bf16(ah1, bl1.b, acc11, 0, 0, 0); \
    acc11 = __builtin_amdgcn_mfma_f32_16x16x32_bf16(al1, bh1.b, acc11, 0, 0, 0); \
  }
  for (int s = 0; s < NSTEPS; s += 2) {
    STEP(s,     pa0A, pa1A, buA, buB)
    STEP(s + 1, pa0B, pa1B, buB, buA)
  }
#undef STEP
  __syncthreads();
#pragma unroll
  for (int r = 0; r < 4; ++r) {
    const int rowb = 32 * wip + 4 * q + r;
    const int colb = 32 * wjp + l15;
    hat[rowb * HAT_STRIDE + colb]             = acc00[r];
    hat[rowb * HAT_STRIDE + colb + 16]        = acc01[r];
    hat[(rowb + 16) * HAT_STRIDE + colb]      = acc10[r];
    hat[(rowb + 16) * HAT_STRIDE + colb + 16] = acc11[r];
  }
  __syncthreads();
  if (t < BM) {
    const int r = t;
    float bb[N_CAP];
#pragma unroll
    for (int n = 0; n < N_CAP; ++n) bb[n] = 0.f;
    float v[D_CAP];
#pragma unroll
    for (int it = 0; it < 3; ++it) {
      float mx = bb[0];
#pragma unroll
      for (int n = 1; n < N_CAP; ++n) mx = fmaxf(mx, bb[n]);
      float c[N_CAP], se = 0.f;
#pragma unroll
      for (int n = 0; n < N_CAP; ++n) { c[n] = __expf(bb[n] - mx); se += c[n]; }
      const float inv = 1.f / se;
      float sd[D_CAP], s2 = 0.f;
#pragma unroll
      for (int d = 0; d < D_CAP; ++d) {
        float x = 0.f;
#pragma unroll
        for (int n = 0; n < N_CAP; ++n) x += c[n] * hat[r * HAT_STRIDE + n * D_CAP + d];
        x *= inv;
        sd[d] = x;
        s2 += x * x;
      }
      const float scale = s2 / ((1.f + s2) * sqrtf(s2 + 1e-7f));
#pragma unroll
      for (int d = 0; d < D_CAP; ++d) v[d] = scale * sd[d];
      if (it < 2) {
#pragma unroll
        for (int n = 0; n < N_CAP; ++n) {
          float dd = 0.f;
#pragma unroll
          for (int d = 0; d < D_CAP; ++d) dd += hat[r * HAT_STRIDE + n * D_CAP + d] * v[d];
          bb[n] += dd;
        }
      }
    }
#pragma unroll
    for (int d = 0; d < D_CAP; ++d)
      out[(size_t)(rbase + r) * D_CAP + d] = v[d];
  }
}

extern "C" void kernel_launch(void* const* d_in, const int* in_sizes, int n_in,
                              void* d_out, int out_size, void* d_ws, size_t ws_size,
                              hipStream_t stream) {
  const float* X = (const float*)d_in[0];   // inputs [16384][2048] f32
  const float* W = (const float*)d_in[1];   // kernel [2048][160] f32
  if (n_in >= 2 && in_sizes[0] == KK * NN) {
    X = (const float*)d_in[1];
    W = (const float*)d_in[0];
  }
  if (ws_size >= WS_NEED) {   // 22.3 MB: Whi+Wlo (1.25 MB) + partials (21 MB)
    u16* Whi = (u16*)d_ws;
    u16* Wlo = Whi + (size_t)KK * NN;
    float* P = (float*)((char*)d_ws + P_OFF_BYTES);
    split_w<<<(KK * NN) / 256, 256, 0, stream>>>(W, Whi, Wlo);
    gemm_splitk<<<256, THRm, 0, stream>>>(X, Whi, Wlo, P);
    reduce_route<<<256, 64, 0, stream>>>(P, (float*)d_out);
  } else {
    capsule_fb<<<16384 / BM, THREADS, 0, stream>>>(X, W, (float*)d_out);
  }
}